// Round 3
// baseline (2714.923 us; speedup 1.0000x reference)
//
#include <hip/hip_runtime.h>

#define NN 1048576   // nodes
#define NE 8388608   // edges
#define NG 16384     // graphs
#define NC 10        // classes

// ---------------- node embedding: h = x @ W_emb^T + b_emb ----------------
__global__ __launch_bounds__(256) void k_embed(const float* __restrict__ x,
    const float* __restrict__ W, const float* __restrict__ b, float* __restrict__ h) {
  __shared__ float sW[160];
  __shared__ float sb[32];
  int t = threadIdx.x;
  if (t < 160) sW[t] = W[t];
  if (t < 32) sb[t] = b[t];
  __syncthreads();
  int idx = blockIdx.x * 256 + t;      // (node, channel)
  int c = idx & 31, n = idx >> 5;
  const float* xr = x + n * 5;
  float acc = sb[c];
#pragma unroll
  for (int k = 0; k < 5; ++k) acc = fmaf(xr[k], sW[c * 5 + k], acc);
  h[idx] = acc;
}

// ---------------- edge scatter: agg[dst] += ew * h[src] ----------------
__global__ __launch_bounds__(256) void k_scatter(const int* __restrict__ ei,
    const float* __restrict__ ew, const float* __restrict__ h, float* __restrict__ agg) {
  int idx = blockIdx.x * 256 + threadIdx.x;   // (edge, channel)
  int c = idx & 31, e = idx >> 5;
  int s = ei[e], d = ei[NE + e];
  float w = ew[e];
  atomicAdd(&agg[d * 32 + c], w * h[s * 32 + c]);
}

// ------- per-node linear: agg = agg@Wrel^T + brel + h@Wroot^T  (+BN stats) -------
__global__ __launch_bounds__(256) void k_lin(const float* __restrict__ Wrel,
    const float* __restrict__ brel, const float* __restrict__ Wroot,
    const float* __restrict__ h, float* __restrict__ agg, double* __restrict__ stats) {
  __shared__ float sWr[1024], sWo[1024], sb[32];   // transposed [k][c]
  __shared__ float sA[256], sH[256];
  __shared__ double rS[256], rQ[256];
  int t = threadIdx.x;
  for (int i = t; i < 1024; i += 256) {
    int c = i >> 5, k = i & 31;
    sWr[k * 32 + c] = Wrel[i];
    sWo[k * 32 + c] = Wroot[i];
  }
  if (t < 32) sb[t] = brel[t];
  __syncthreads();
  int c = t & 31, lr = t >> 5;     // 8 nodes per iteration
  double aS = 0.0, aQ = 0.0;
  for (int base = blockIdx.x * 8; base < NN; base += gridDim.x * 8) {
    int g = base * 32 + t;
    sA[t] = agg[g];
    sH[t] = h[g];
    __syncthreads();
    float acc = sb[c];
#pragma unroll
    for (int k = 0; k < 32; ++k)
      acc = fmaf(sA[lr * 32 + k], sWr[k * 32 + c], fmaf(sH[lr * 32 + k], sWo[k * 32 + c], acc));
    agg[g] = acc;          // in-place safe: row staged in LDS, rows block-private
    aS += acc;
    aQ += (double)acc * acc;
    __syncthreads();
  }
  rS[t] = aS; rQ[t] = aQ;
  __syncthreads();
  for (int s = 128; s >= 32; s >>= 1) {
    if (t < s) { rS[t] += rS[t + s]; rQ[t] += rQ[t + s]; }
    __syncthreads();
  }
  if (t < 32) {
    atomicAdd(&stats[t], rS[t]);
    atomicAdd(&stats[32 + t], rQ[t]);
  }
}

// ---------------- finalize BN: scale/shift per channel ----------------
__global__ void k_bnfin(const double* __restrict__ stats, const float* __restrict__ gamma,
                        const float* __restrict__ beta, float* __restrict__ ss) {
  int c = threadIdx.x;
  double mean = stats[c] * (1.0 / NN);
  double var = stats[32 + c] * (1.0 / NN) - mean * mean;
  float scale = gamma[c] * (float)(1.0 / sqrt(var + 1e-5));
  ss[c] = scale;
  ss[32 + c] = beta[c] - (float)mean * scale;
}

// ---------------- BN apply + ReLU (+ optional fused max-pool) ----------------
template <int POOL>
__global__ __launch_bounds__(256) void k_apply(const float* __restrict__ in,
    const float* __restrict__ ss, float* __restrict__ h,
    const int* __restrict__ batch, unsigned* __restrict__ pooled) {
  __shared__ float s0[32], s1[32];
  int t = threadIdx.x;
  if (t < 32) { s0[t] = ss[t]; s1[t] = ss[32 + t]; }
  __syncthreads();
  int idx = blockIdx.x * 256 + t;
  int c = idx & 31;
  float v = fmaxf(fmaf(in[idx], s0[c], s1[c]), 0.f);
  if (POOL) {
    int n = idx >> 5;
    int g = batch[n];
    atomicMax(&pooled[g * 32 + c], __float_as_uint(v));  // v >= 0: uint order == float order
  } else {
    h[idx] = v;
  }
}

// ---------------- MLP head: relu(gx@W1^T+b1)@W2^T+b2 ----------------
__global__ __launch_bounds__(256) void k_head(const float* __restrict__ pooled,
    const float* __restrict__ W1, const float* __restrict__ b1,
    const float* __restrict__ W2, const float* __restrict__ b2, float* __restrict__ out) {
  __shared__ float sW1[64 * 33], sW2[10 * 65], sb1[64], sb2[10];
  __shared__ float sHid[4][64];
  int t = threadIdx.x;
  for (int i = t; i < 2048; i += 256) sW1[(i >> 5) * 33 + (i & 31)] = W1[i];
  for (int i = t; i < 640; i += 256) sW2[(i >> 6) * 65 + (i & 63)] = W2[i];
  if (t < 64) sb1[t] = b1[t];
  if (t < 10) sb2[t] = b2[t];
  __syncthreads();
  int w = t >> 6, lane = t & 63;
  for (int g = blockIdx.x * 4 + w; g < NG; g += gridDim.x * 4) {
    float pv = (lane < 32) ? pooled[g * 32 + lane] : 0.f;
    float acc = sb1[lane];
#pragma unroll
    for (int k = 0; k < 32; ++k)
      acc = fmaf(__shfl(pv, k, 64), sW1[lane * 33 + k], acc);
    acc = fmaxf(acc, 0.f);
    sHid[w][lane] = acc;
    __syncthreads();
    if (lane < 10) {
      float o = sb2[lane];
#pragma unroll
      for (int j = 0; j < 64; ++j) o = fmaf(sHid[w][j], sW2[lane * 65 + j], o);
      out[g * 10 + lane] = o;
    }
    __syncthreads();
  }
}

extern "C" void kernel_launch(void* const* d_in, const int* in_sizes, int n_in,
                              void* d_out, int out_size, void* d_ws, size_t ws_size,
                              hipStream_t stream) {
  const float* x      = (const float*)d_in[0];
  const int*   ei     = (const int*)d_in[1];
  const float* ea     = (const float*)d_in[2];
  const int*   batch  = (const int*)d_in[3];
  const float* W_emb  = (const float*)d_in[4];
  const float* b_emb  = (const float*)d_in[5];
  const float* W_rel  = (const float*)d_in[6];
  const float* b_rel  = (const float*)d_in[7];
  const float* W_root = (const float*)d_in[8];
  const float* gamma  = (const float*)d_in[9];
  const float* beta   = (const float*)d_in[10];
  const float* W1     = (const float*)d_in[11];
  const float* b1     = (const float*)d_in[12];
  const float* W2     = (const float*)d_in[13];
  const float* b2     = (const float*)d_in[14];
  float* out = (float*)d_out;

  // ---- workspace layout: fits in EXACTLY 2*NB = 256 MiB ----
  char* ws = (char*)d_ws;
  size_t NB = (size_t)NN * 32 * 4;                 // 128 MiB per node buffer
  float* h   = (float*)ws;                          // [0, 128 MiB)
  float* agg = (float*)(ws + NB);                   // [128, 256 MiB)
  // pooled aliases h: h is dead after layer-2 k_lin, pooled written after that.
  unsigned* pooled = (unsigned*)ws;                 // NG*32*4 = 2 MiB
  // tiny scalars live in d_out (640 KiB); fully overwritten by k_head at the end.
  double* stats = (double*)d_out;                   // 64 doubles = 512 B
  float*  ss    = (float*)((char*)d_out + 512);     // 64 floats  = 256 B

  (void)hipMemsetAsync(out, 0, 0, stream);

  k_embed<<<NN * 32 / 256, 256, 0, stream>>>(x, W_emb, b_emb, h);

  for (int l = 0; l < 2; ++l) {
    (void)hipMemsetAsync(agg, 0, NB, stream);
    k_scatter<<<NE * 32 / 256, 256, 0, stream>>>(ei, ea, h, agg);
    (void)hipMemsetAsync(stats, 0, 64 * 8, stream);
    k_lin<<<2048, 256, 0, stream>>>(W_rel + l * 1024, b_rel + l * 32, W_root + l * 1024,
                                    h, agg, stats);   // last read of h in layer 2
    k_bnfin<<<1, 32, 0, stream>>>(stats, gamma + l * 32, beta + l * 32, ss);
    if (l == 0) {
      k_apply<0><<<NN * 32 / 256, 256, 0, stream>>>(agg, ss, h, nullptr, nullptr);
    } else {
      (void)hipMemsetAsync(pooled, 0, (size_t)NG * 32 * 4, stream);   // h is dead now
      k_apply<1><<<NN * 32 / 256, 256, 0, stream>>>(agg, ss, nullptr, batch, pooled);
    }
  }
  k_head<<<1024, 256, 0, stream>>>((const float*)pooled, W1, b1, W2, b2, out);
}

// Round 5
// 2369.810 us; speedup vs baseline: 1.1456x; 1.1456x over previous
//
#include <hip/hip_runtime.h>
#include <hip/hip_fp16.h>

#define NN 1048576   // nodes
#define NE 8388608   // edges
#define NG 16384     // graphs

// ---------------- node embedding: hA = f16(x @ W_emb^T + b_emb) ----------------
__global__ __launch_bounds__(256) void k_embed(const float* __restrict__ x,
    const float* __restrict__ W, const float* __restrict__ b, __half* __restrict__ h) {
  __shared__ float sW[160];
  __shared__ float sb[32];
  int t = threadIdx.x;
  if (t < 160) sW[t] = W[t];
  if (t < 32) sb[t] = b[t];
  __syncthreads();
  int idx = blockIdx.x * 256 + t;      // (node, channel)
  int c = idx & 31, n = idx >> 5;
  const float* xr = x + n * 5;
  float acc = sb[c];
#pragma unroll
  for (int k = 0; k < 5; ++k) acc = fmaf(xr[k], sW[c * 5 + k], acc);
  h[idx] = __float2half(acc);
}

// ---------------- CSR build: histogram ----------------
__global__ __launch_bounds__(256) void k_hist(const int* __restrict__ dst, int* __restrict__ deg) {
  int e = blockIdx.x * 256 + threadIdx.x;
  atomicAdd(&deg[dst[e]], 1);
}

// ---------------- scan stage 1: per-block (1024 elems) sums ----------------
__global__ __launch_bounds__(256) void k_scan1(const int* __restrict__ deg, int* __restrict__ bsum) {
  __shared__ int s[256];
  int t = threadIdx.x;
  int base = blockIdx.x * 1024 + t * 4;
  int v = deg[base] + deg[base + 1] + deg[base + 2] + deg[base + 3];
  s[t] = v; __syncthreads();
  for (int st = 128; st > 0; st >>= 1) {
    if (t < st) s[t] += s[t + st];
    __syncthreads();
  }
  if (t == 0) bsum[blockIdx.x] = s[0];
}

// ---------------- scan stage 2: exclusive scan of 1024 block sums ----------------
__global__ __launch_bounds__(1024) void k_scan2(int* __restrict__ bsum) {
  __shared__ int s[1024];
  int t = threadIdx.x;
  int v = bsum[t];
  s[t] = v; __syncthreads();
  for (int st = 1; st < 1024; st <<= 1) {
    int a = (t >= st) ? s[t - st] : 0;
    __syncthreads();
    s[t] += a;
    __syncthreads();
  }
  bsum[t] = s[t] - v;   // exclusive
}

// ---------------- scan stage 3: rowptr + cursor init ----------------
__global__ __launch_bounds__(256) void k_scan3(const int* __restrict__ deg, const int* __restrict__ bsum,
                                               int* __restrict__ rowptr, int* __restrict__ cur) {
  __shared__ int s[256];
  int t = threadIdx.x;
  int base = blockIdx.x * 1024 + t * 4;
  int d0 = deg[base], d1 = deg[base + 1], d2 = deg[base + 2], d3 = deg[base + 3];
  int tsum = d0 + d1 + d2 + d3;
  s[t] = tsum; __syncthreads();
  for (int st = 1; st < 256; st <<= 1) {   // inclusive scan over thread sums
    int a = (t >= st) ? s[t - st] : 0;
    __syncthreads();
    s[t] += a;
    __syncthreads();
  }
  int ex = s[t] - tsum + bsum[blockIdx.x];
  int p0 = ex, p1 = ex + d0, p2 = p1 + d1, p3 = p2 + d2;
  rowptr[base] = p0; rowptr[base + 1] = p1; rowptr[base + 2] = p2; rowptr[base + 3] = p3;
  cur[base] = p0; cur[base + 1] = p1; cur[base + 2] = p2; cur[base + 3] = p3;
  if (blockIdx.x == 1023 && t == 255) rowptr[NN] = NE;
}

// ---------------- CSR fill: colw[pos] = (src, w_bits) ----------------
__global__ __launch_bounds__(256) void k_fill(const int* __restrict__ ei, const float* __restrict__ ew,
                                              int* __restrict__ cur, uint2* __restrict__ colw) {
  int e = blockIdx.x * 256 + threadIdx.x;
  int s = ei[e], d = ei[NE + e];
  float w = ew[e];
  int p = atomicAdd(&cur[d], 1);
  colw[p] = make_uint2((unsigned)s, __float_as_uint(w));
}

// ------ fused pull-aggregate + dual 32x32 linear + BN-stat accumulation ------
// group of 32 lanes owns one node; no atomics, no memset, no global agg buffer
__global__ __launch_bounds__(256) void k_agglin(
    const int* __restrict__ rowptr, const uint2* __restrict__ colw,
    const __half* __restrict__ hIn, const float* __restrict__ Wrel,
    const float* __restrict__ brel, const float* __restrict__ Wroot,
    __half* __restrict__ hPre, double* __restrict__ stats) {
  __shared__ float sWr[1024], sWo[1024], sb[32];   // transposed [k][c]
  __shared__ float sv[256], sh[256];
  __shared__ double rS[256], rQ[256];
  int t = threadIdx.x;
  for (int i = t; i < 1024; i += 256) {
    int c = i >> 5, k = i & 31;
    sWr[k * 32 + c] = Wrel[i];
    sWo[k * 32 + c] = Wroot[i];
  }
  if (t < 32) sb[t] = brel[t];
  __syncthreads();
  int c = t & 31, grp = t >> 5;     // 8 nodes in flight per block
  double aS = 0.0, aQ = 0.0;
  for (int n0 = blockIdx.x * 8; n0 < NN; n0 += gridDim.x * 8) {
    int n = n0 + grp;
    int r0 = rowptr[n], r1 = rowptr[n + 1];
    float acc = 0.f;
    for (int j = r0; j < r1; j += 32) {
      int m = r1 - j;
      uint2 cw;
      if (c < m) cw = colw[j + c];                  // coalesced 256 B per group
      int cnt = min(m, 32);
      for (int i = 0; i < cnt; ++i) {
        unsigned src = __shfl(cw.x, i, 32);         // broadcast edge to group
        float w = __uint_as_float(__shfl(cw.y, i, 32));
        acc = fmaf(w, __half2float(hIn[(size_t)src * 32 + c]), acc);  // 64 B row read
      }
    }
    float hv = __half2float(hIn[(size_t)n * 32 + c]);
    // group-private LDS slice; group = half-wave, wave-ordered LDS => no barrier
    sv[t] = acc; sh[t] = hv;
    float o = sb[c];
#pragma unroll
    for (int k = 0; k < 32; ++k)
      o = fmaf(sv[grp * 32 + k], sWr[k * 32 + c], fmaf(sh[grp * 32 + k], sWo[k * 32 + c], o));
    hPre[(size_t)n * 32 + c] = __float2half(o);
    aS += o; aQ += (double)o * o;
  }
  rS[t] = aS; rQ[t] = aQ;
  __syncthreads();
  for (int s = 128; s >= 32; s >>= 1) {
    if (t < s) { rS[t] += rS[t + s]; rQ[t] += rQ[t + s]; }
    __syncthreads();
  }
  if (t < 32) {
    atomicAdd(&stats[t], rS[t]);
    atomicAdd(&stats[32 + t], rQ[t]);
  }
}

// ---------------- finalize BN: scale/shift per channel ----------------
__global__ void k_bnfin(const double* __restrict__ stats, const float* __restrict__ gamma,
                        const float* __restrict__ beta, float* __restrict__ ss) {
  int c = threadIdx.x;
  double mean = stats[c] * (1.0 / NN);
  double var = stats[32 + c] * (1.0 / NN) - mean * mean;
  float scale = gamma[c] * (float)(1.0 / sqrt(var + 1e-5));
  ss[c] = scale;
  ss[32 + c] = beta[c] - (float)mean * scale;
}

// ---------------- BN apply + ReLU (+ optional fused max-pool) ----------------
template <int POOL>
__global__ __launch_bounds__(256) void k_apply(const __half* __restrict__ in,
    const float* __restrict__ ss, __half* __restrict__ outp,
    const int* __restrict__ batch, unsigned* __restrict__ pooled) {
  __shared__ float s0[32], s1[32];
  int t = threadIdx.x;
  if (t < 32) { s0[t] = ss[t]; s1[t] = ss[32 + t]; }
  __syncthreads();
  int idx = blockIdx.x * 256 + t;
  int c = idx & 31;
  float v = fmaxf(fmaf(__half2float(in[idx]), s0[c], s1[c]), 0.f);
  if (POOL) {
    int g = batch[idx >> 5];
    atomicMax(&pooled[g * 32 + c], __float_as_uint(v));  // v >= 0: uint order == float order
  } else {
    outp[idx] = __float2half(v);
  }
}

// ---------------- MLP head: relu(gx@W1^T+b1)@W2^T+b2 ----------------
__global__ __launch_bounds__(256) void k_head(const float* __restrict__ pooled,
    const float* __restrict__ W1, const float* __restrict__ b1,
    const float* __restrict__ W2, const float* __restrict__ b2, float* __restrict__ out) {
  __shared__ float sW1[64 * 33], sW2[10 * 65], sb1[64], sb2[10];
  __shared__ float sHid[4][64];
  int t = threadIdx.x;
  for (int i = t; i < 2048; i += 256) sW1[(i >> 5) * 33 + (i & 31)] = W1[i];
  for (int i = t; i < 640; i += 256) sW2[(i >> 6) * 65 + (i & 63)] = W2[i];
  if (t < 64) sb1[t] = b1[t];
  if (t < 10) sb2[t] = b2[t];
  __syncthreads();
  int w = t >> 6, lane = t & 63;
  for (int g = blockIdx.x * 4 + w; g < NG; g += gridDim.x * 4) {
    float pv = (lane < 32) ? pooled[g * 32 + lane] : 0.f;
    float acc = sb1[lane];
#pragma unroll
    for (int k = 0; k < 32; ++k)
      acc = fmaf(__shfl(pv, k, 64), sW1[lane * 33 + k], acc);
    acc = fmaxf(acc, 0.f);
    sHid[w][lane] = acc;
    __syncthreads();
    if (lane < 10) {
      float o = sb2[lane];
#pragma unroll
      for (int j = 0; j < 64; ++j) o = fmaf(sHid[w][j], sW2[lane * 65 + j], o);
      out[g * 10 + lane] = o;
    }
    __syncthreads();
  }
}

extern "C" void kernel_launch(void* const* d_in, const int* in_sizes, int n_in,
                              void* d_out, int out_size, void* d_ws, size_t ws_size,
                              hipStream_t stream) {
  const float* x      = (const float*)d_in[0];
  const int*   ei     = (const int*)d_in[1];
  const float* ea     = (const float*)d_in[2];
  const int*   batch  = (const int*)d_in[3];
  const float* W_emb  = (const float*)d_in[4];
  const float* b_emb  = (const float*)d_in[5];
  const float* W_rel  = (const float*)d_in[6];
  const float* b_rel  = (const float*)d_in[7];
  const float* W_root = (const float*)d_in[8];
  const float* gamma  = (const float*)d_in[9];
  const float* beta   = (const float*)d_in[10];
  const float* W1     = (const float*)d_in[11];
  const float* b1     = (const float*)d_in[12];
  const float* W2     = (const float*)d_in[13];
  const float* b2     = (const float*)d_in[14];
  float* out = (float*)d_out;

  // ---- workspace layout (~203 MiB of the 256 MiB budget) ----
  char* ws = (char*)d_ws;
  size_t off = 0;
  __half* hA     = (__half*)(ws + off); off += (size_t)NN * 32 * 2;        // 64 MiB
  __half* hB     = (__half*)(ws + off); off += (size_t)NN * 32 * 2;        // 64 MiB
  uint2*  colw   = (uint2*)(ws + off);  off += (size_t)NE * 8;             // 64 MiB
  int*    rowptr = (int*)(ws + off);    off += ((size_t)NN + 64) * 4;      // 4 MiB + pad
  int*    cur    = (int*)(ws + off);    off += (size_t)NN * 4;             // 4 MiB (also deg)
  int*    bsum   = (int*)(ws + off);    off += 4096;                       // 1024 ints
  unsigned* pooled = (unsigned*)(ws + off);                                // 2 MiB
  // tiny scalars in d_out; fully overwritten by k_head at the end
  double* stats = (double*)d_out;                   // 64 doubles = 512 B
  float*  ss    = (float*)((char*)d_out + 512);     // 64 floats  = 256 B

  k_embed<<<NN * 32 / 256, 256, 0, stream>>>(x, W_emb, b_emb, hA);

  // ---- build CSR once (shared by both layers) ----
  (void)hipMemsetAsync(cur, 0, (size_t)NN * 4, stream);
  k_hist <<<NE / 256, 256, 0, stream>>>(ei + NE, cur);
  k_scan1<<<1024, 256, 0, stream>>>(cur, bsum);
  k_scan2<<<1, 1024, 0, stream>>>(bsum);
  k_scan3<<<1024, 256, 0, stream>>>(cur, bsum, rowptr, cur);
  k_fill <<<NE / 256, 256, 0, stream>>>(ei, ea, cur, colw);

  for (int l = 0; l < 2; ++l) {
    (void)hipMemsetAsync(stats, 0, 64 * 8, stream);
    k_agglin<<<2048, 256, 0, stream>>>(rowptr, colw, hA, W_rel + l * 1024, b_rel + l * 32,
                                       W_root + l * 1024, hB, stats);
    k_bnfin<<<1, 32, 0, stream>>>(stats, gamma + l * 32, beta + l * 32, ss);
    if (l == 0) {
      k_apply<0><<<NN * 32 / 256, 256, 0, stream>>>(hB, ss, hA, nullptr, nullptr);
    } else {
      (void)hipMemsetAsync(pooled, 0, (size_t)NG * 32 * 4, stream);
      k_apply<1><<<NN * 32 / 256, 256, 0, stream>>>(hB, ss, nullptr, batch, pooled);
    }
  }
  k_head<<<1024, 256, 0, stream>>>((const float*)pooled, W1, b1, W2, b2, out);
}

// Round 7
// 1767.055 us; speedup vs baseline: 1.5364x; 1.3411x over previous
//
#include <hip/hip_runtime.h>
#include <hip/hip_fp16.h>

#define NN 1048576   // nodes
#define NE 8388608   // edges
#define NG 16384     // graphs

// ---------------- node embedding: hA = f16(x @ W_emb^T + b_emb) ----------------
__global__ __launch_bounds__(256) void k_embed(const float* __restrict__ x,
    const float* __restrict__ W, const float* __restrict__ b, __half* __restrict__ h) {
  __shared__ float sW[160];
  __shared__ float sb[32];
  int t = threadIdx.x;
  if (t < 160) sW[t] = W[t];
  if (t < 32) sb[t] = b[t];
  __syncthreads();
  int idx = blockIdx.x * 256 + t;      // (node, channel)
  int c = idx & 31, n = idx >> 5;
  const float* xr = x + n * 5;
  float acc = sb[c];
#pragma unroll
  for (int k = 0; k < 5; ++k) acc = fmaf(xr[k], sW[c * 5 + k], acc);
  h[idx] = __float2half(acc);
}

// ---------------- CSR build: histogram ----------------
__global__ __launch_bounds__(256) void k_hist(const int* __restrict__ dst, int* __restrict__ deg) {
  int e = blockIdx.x * 256 + threadIdx.x;
  atomicAdd(&deg[dst[e]], 1);
}

// ---------------- scan stage 1: per-block (1024 elems) sums ----------------
__global__ __launch_bounds__(256) void k_scan1(const int* __restrict__ deg, int* __restrict__ bsum) {
  __shared__ int s[256];
  int t = threadIdx.x;
  int base = blockIdx.x * 1024 + t * 4;
  int v = deg[base] + deg[base + 1] + deg[base + 2] + deg[base + 3];
  s[t] = v; __syncthreads();
  for (int st = 128; st > 0; st >>= 1) {
    if (t < st) s[t] += s[t + st];
    __syncthreads();
  }
  if (t == 0) bsum[blockIdx.x] = s[0];
}

// ---------------- scan stage 2: exclusive scan of 1024 block sums ----------------
__global__ __launch_bounds__(1024) void k_scan2(int* __restrict__ bsum) {
  __shared__ int s[1024];
  int t = threadIdx.x;
  int v = bsum[t];
  s[t] = v; __syncthreads();
  for (int st = 1; st < 1024; st <<= 1) {
    int a = (t >= st) ? s[t - st] : 0;
    __syncthreads();
    s[t] += a;
    __syncthreads();
  }
  bsum[t] = s[t] - v;   // exclusive
}

// ---------------- scan stage 3: rowptr + cursor init ----------------
__global__ __launch_bounds__(256) void k_scan3(const int* __restrict__ deg, const int* __restrict__ bsum,
                                               int* __restrict__ rowptr, int* __restrict__ cur) {
  __shared__ int s[256];
  int t = threadIdx.x;
  int base = blockIdx.x * 1024 + t * 4;
  int d0 = deg[base], d1 = deg[base + 1], d2 = deg[base + 2], d3 = deg[base + 3];
  int tsum = d0 + d1 + d2 + d3;
  s[t] = tsum; __syncthreads();
  for (int st = 1; st < 256; st <<= 1) {   // inclusive scan over thread sums
    int a = (t >= st) ? s[t - st] : 0;
    __syncthreads();
    s[t] += a;
    __syncthreads();
  }
  int ex = s[t] - tsum + bsum[blockIdx.x];
  int p0 = ex, p1 = ex + d0, p2 = p1 + d1, p3 = p2 + d2;
  rowptr[base] = p0; rowptr[base + 1] = p1; rowptr[base + 2] = p2; rowptr[base + 3] = p3;
  cur[base] = p0; cur[base + 1] = p1; cur[base + 2] = p2; cur[base + 3] = p3;
  if (blockIdx.x == 1023 && t == 255) rowptr[NN] = NE;
}

// ---------------- CSR fill: colw[pos] = (src, w_bits) ----------------
__global__ __launch_bounds__(256) void k_fill(const int* __restrict__ ei, const float* __restrict__ ew,
                                              int* __restrict__ cur, uint2* __restrict__ colw) {
  int e = blockIdx.x * 256 + threadIdx.x;
  int s = ei[e], d = ei[NE + e];
  float w = ew[e];
  int p = atomicAdd(&cur[d], 1);
  colw[p] = make_uint2((unsigned)s, __float_as_uint(w));
}

// ---------------- graph rowptr from sorted batch: boundary detection ----------------
__global__ __launch_bounds__(256) void k_gbound(const int* __restrict__ batch, int* __restrict__ gptr) {
  int n = blockIdx.x * 256 + threadIdx.x;
  int b = batch[n];
  int prev = (n == 0) ? -1 : batch[n - 1];
  for (int g = prev + 1; g <= b; ++g) gptr[g] = n;   // covers skipped (empty) graphs too
  if (n == NN - 1) {
    for (int g = b + 1; g <= NG; ++g) gptr[g] = NN;
  }
}

// ------ fused pull-aggregate + dual 32x32 linear + BN-stat accumulation ------
// group of 32 lanes owns one node; 8 gather loads in flight per group (latency fix)
__global__ __launch_bounds__(256) void k_agglin(
    const int* __restrict__ rowptr, const uint2* __restrict__ colw,
    const __half* __restrict__ hIn, const float* __restrict__ Wrel,
    const float* __restrict__ brel, const float* __restrict__ Wroot,
    __half* __restrict__ hPre, double* __restrict__ stats) {
  __shared__ float sWr[1024], sWo[1024], sb[32];   // transposed [k][c]
  __shared__ uint2 sE[256];                        // staged edge records (per-group slice)
  __shared__ float sv[256], sh[256];
  __shared__ double rS[256], rQ[256];
  int t = threadIdx.x;
  for (int i = t; i < 1024; i += 256) {
    int cc = i >> 5, k = i & 31;
    sWr[k * 32 + cc] = Wrel[i];
    sWo[k * 32 + cc] = Wroot[i];
  }
  if (t < 32) sb[t] = brel[t];
  __syncthreads();
  int c = t & 31, grp = t >> 5;     // 8 nodes in flight per block
  double aS = 0.0, aQ = 0.0;
  for (int n0 = blockIdx.x * 8; n0 < NN; n0 += gridDim.x * 8) {
    int n = n0 + grp;
    int r0 = rowptr[n], r1 = rowptr[n + 1];
    float acc = 0.f;
    for (int j = r0; j < r1; j += 32) {
      int m = r1 - j; if (m > 32) m = 32;
      uint2 cw = make_uint2(0u, 0u);               // pad: src=0 (valid row), w=+0
      if (c < m) cw = colw[j + c];                 // coalesced 256 B per group
      sE[t] = cw;                                  // same-wave LDS: no barrier needed
      int mm = (m + 7) & ~7;
      for (int i = 0; i < mm; i += 8) {
        const uint2* eb = &sE[grp * 32 + i];       // broadcast reads (uniform per group)
        uint2 e0 = eb[0], e1 = eb[1], e2 = eb[2], e3 = eb[3];
        uint2 e4 = eb[4], e5 = eb[5], e6 = eb[6], e7 = eb[7];
        // 8 independent 2 B gathers -> 8 loads in flight
        float h0 = __half2float(hIn[(size_t)e0.x * 32 + c]);
        float h1 = __half2float(hIn[(size_t)e1.x * 32 + c]);
        float h2 = __half2float(hIn[(size_t)e2.x * 32 + c]);
        float h3 = __half2float(hIn[(size_t)e3.x * 32 + c]);
        float h4 = __half2float(hIn[(size_t)e4.x * 32 + c]);
        float h5 = __half2float(hIn[(size_t)e5.x * 32 + c]);
        float h6 = __half2float(hIn[(size_t)e6.x * 32 + c]);
        float h7 = __half2float(hIn[(size_t)e7.x * 32 + c]);
        acc = fmaf(__uint_as_float(e0.y), h0, acc);
        acc = fmaf(__uint_as_float(e1.y), h1, acc);
        acc = fmaf(__uint_as_float(e2.y), h2, acc);
        acc = fmaf(__uint_as_float(e3.y), h3, acc);
        acc = fmaf(__uint_as_float(e4.y), h4, acc);
        acc = fmaf(__uint_as_float(e5.y), h5, acc);
        acc = fmaf(__uint_as_float(e6.y), h6, acc);
        acc = fmaf(__uint_as_float(e7.y), h7, acc);
      }
    }
    float hv = __half2float(hIn[(size_t)n * 32 + c]);
    // group-private LDS slice; group = half-wave, wave-ordered LDS => no barrier
    sv[t] = acc; sh[t] = hv;
    float o = sb[c];
#pragma unroll
    for (int k = 0; k < 32; ++k)
      o = fmaf(sv[grp * 32 + k], sWr[k * 32 + c], fmaf(sh[grp * 32 + k], sWo[k * 32 + c], o));
    hPre[(size_t)n * 32 + c] = __float2half(o);
    aS += o; aQ += (double)o * o;
  }
  rS[t] = aS; rQ[t] = aQ;
  __syncthreads();
  for (int s = 128; s >= 32; s >>= 1) {
    if (t < s) { rS[t] += rS[t + s]; rQ[t] += rQ[t + s]; }
    __syncthreads();
  }
  if (t < 32) {
    atomicAdd(&stats[t], rS[t]);
    atomicAdd(&stats[32 + t], rQ[t]);
  }
}

// ---------------- finalize BN: scale/shift per channel ----------------
__global__ void k_bnfin(const double* __restrict__ stats, const float* __restrict__ gamma,
                        const float* __restrict__ beta, float* __restrict__ ss) {
  int c = threadIdx.x;
  double mean = stats[c] * (1.0 / NN);
  double var = stats[32 + c] * (1.0 / NN) - mean * mean;
  float scale = gamma[c] * (float)(1.0 / sqrt(var + 1e-5));
  ss[c] = scale;
  ss[32 + c] = beta[c] - (float)mean * scale;
}

// ---------------- BN apply + ReLU (layer 1) ----------------
__global__ __launch_bounds__(256) void k_apply(const __half* __restrict__ in,
    const float* __restrict__ ss, __half* __restrict__ outp) {
  __shared__ float s0[32], s1[32];
  int t = threadIdx.x;
  if (t < 32) { s0[t] = ss[t]; s1[t] = ss[32 + t]; }
  __syncthreads();
  int idx = blockIdx.x * 256 + t;
  int c = idx & 31;
  float v = fmaxf(fmaf(__half2float(in[idx]), s0[c], s1[c]), 0.f);
  outp[idx] = __float2half(v);
}

// ------- layer-2 BN apply + ReLU + segment-max pool: one wave per graph, no atomics -------
__global__ __launch_bounds__(256) void k_pool(const __half* __restrict__ hB,
    const float* __restrict__ ss, const int* __restrict__ gptr, float* __restrict__ pooled) {
  __shared__ float s0[32], s1[32];
  int t = threadIdx.x;
  if (t < 32) { s0[t] = ss[t]; s1[t] = ss[32 + t]; }
  __syncthreads();
  int wv = t >> 6, lane = t & 63;
  int c = lane & 31, p = lane >> 5;          // 2 nodes per wave iteration
  int g = blockIdx.x * 4 + wv;               // grid 4096 x 4 waves = NG exactly
  int a = gptr[g], b = gptr[g + 1];
  float mx = 0.f;                             // post-ReLU max is >= 0
  for (int n = a + p; n < b; n += 2)
    mx = fmaxf(mx, fmaf(__half2float(hB[(size_t)n * 32 + c]), s0[c], s1[c]));
  mx = fmaxf(mx, __shfl_xor(mx, 32, 64));     // combine the two node-slots
  if (p == 0) pooled[g * 32 + c] = mx;        // == relu(max) since mx init 0
}

// ---------------- MLP head: relu(gx@W1^T+b1)@W2^T+b2 ----------------
__global__ __launch_bounds__(256) void k_head(const float* __restrict__ pooled,
    const float* __restrict__ W1, const float* __restrict__ b1,
    const float* __restrict__ W2, const float* __restrict__ b2, float* __restrict__ out) {
  __shared__ float sW1[64 * 33], sW2[10 * 65], sb1[64], sb2[10];
  __shared__ float sHid[4][64];
  int t = threadIdx.x;
  for (int i = t; i < 2048; i += 256) sW1[(i >> 5) * 33 + (i & 31)] = W1[i];
  for (int i = t; i < 640; i += 256) sW2[(i >> 6) * 65 + (i & 63)] = W2[i];
  if (t < 64) sb1[t] = b1[t];
  if (t < 10) sb2[t] = b2[t];
  __syncthreads();
  int w = t >> 6, lane = t & 63;
  for (int g = blockIdx.x * 4 + w; g < NG; g += gridDim.x * 4) {
    float pv = (lane < 32) ? pooled[g * 32 + lane] : 0.f;
    float acc = sb1[lane];
#pragma unroll
    for (int k = 0; k < 32; ++k)
      acc = fmaf(__shfl(pv, k, 64), sW1[lane * 33 + k], acc);
    acc = fmaxf(acc, 0.f);
    sHid[w][lane] = acc;
    __syncthreads();
    if (lane < 10) {
      float o = sb2[lane];
#pragma unroll
      for (int j = 0; j < 64; ++j) o = fmaf(sHid[w][j], sW2[lane * 65 + j], o);
      out[g * 10 + lane] = o;
    }
    __syncthreads();
  }
}

extern "C" void kernel_launch(void* const* d_in, const int* in_sizes, int n_in,
                              void* d_out, int out_size, void* d_ws, size_t ws_size,
                              hipStream_t stream) {
  const float* x      = (const float*)d_in[0];
  const int*   ei     = (const int*)d_in[1];
  const float* ea     = (const float*)d_in[2];
  const int*   batch  = (const int*)d_in[3];
  const float* W_emb  = (const float*)d_in[4];
  const float* b_emb  = (const float*)d_in[5];
  const float* W_rel  = (const float*)d_in[6];
  const float* b_rel  = (const float*)d_in[7];
  const float* W_root = (const float*)d_in[8];
  const float* gamma  = (const float*)d_in[9];
  const float* beta   = (const float*)d_in[10];
  const float* W1     = (const float*)d_in[11];
  const float* b1     = (const float*)d_in[12];
  const float* W2     = (const float*)d_in[13];
  const float* b2     = (const float*)d_in[14];
  float* out = (float*)d_out;

  // ---- workspace layout (~205 MiB) ----
  char* ws = (char*)d_ws;
  size_t off = 0;
  __half* hA     = (__half*)(ws + off); off += (size_t)NN * 32 * 2;        // 64 MiB
  __half* hB     = (__half*)(ws + off); off += (size_t)NN * 32 * 2;        // 64 MiB
  uint2*  colw   = (uint2*)(ws + off);  off += (size_t)NE * 8;             // 64 MiB
  int*    rowptr = (int*)(ws + off);    off += ((size_t)NN + 64) * 4;      // 4 MiB + pad
  int*    cur    = (int*)(ws + off);    off += (size_t)NN * 4;             // 4 MiB (also deg)
  int*    bsum   = (int*)(ws + off);    off += 4096;                       // 1024 ints
  int*    gptr   = (int*)(ws + off);    off += ((size_t)NG + 64) * 4;      // 64 KiB + pad
  float*  pooled = (float*)(ws + off);                                     // 2 MiB
  // tiny scalars in d_out; fully overwritten by k_head at the end
  double* stats = (double*)d_out;                   // 64 doubles = 512 B
  float*  ss    = (float*)((char*)d_out + 512);     // 64 floats  = 256 B

  k_embed<<<NN * 32 / 256, 256, 0, stream>>>(x, W_emb, b_emb, hA);

  // ---- build CSR + graph ranges once ----
  (void)hipMemsetAsync(cur, 0, (size_t)NN * 4, stream);
  k_hist <<<NE / 256, 256, 0, stream>>>(ei + NE, cur);
  k_scan1<<<1024, 256, 0, stream>>>(cur, bsum);
  k_scan2<<<1, 1024, 0, stream>>>(bsum);
  k_scan3<<<1024, 256, 0, stream>>>(cur, bsum, rowptr, cur);
  k_fill <<<NE / 256, 256, 0, stream>>>(ei, ea, cur, colw);
  k_gbound<<<NN / 256, 256, 0, stream>>>(batch, gptr);

  for (int l = 0; l < 2; ++l) {
    (void)hipMemsetAsync(stats, 0, 64 * 8, stream);
    k_agglin<<<2048, 256, 0, stream>>>(rowptr, colw, hA, W_rel + l * 1024, b_rel + l * 32,
                                       W_root + l * 1024, hB, stats);
    k_bnfin<<<1, 32, 0, stream>>>(stats, gamma + l * 32, beta + l * 32, ss);
    if (l == 0) {
      k_apply<<<NN * 32 / 256, 256, 0, stream>>>(hB, ss, hA);
    } else {
      k_pool<<<NG / 4, 256, 0, stream>>>(hB, ss, gptr, pooled);
    }
  }
  k_head<<<1024, 256, 0, stream>>>(pooled, W1, b1, W2, b2, out);
}